// Round 7
// baseline (313.396 us; speedup 1.0000x reference)
//
#include <hip/hip_runtime.h>

#define NN 50000
#define D 128
#define BM 32

typedef unsigned int uint;
typedef unsigned short ushort;

static __device__ __forceinline__ ushort f2bf(float f) {
    uint u = __float_as_uint(f);
    u = (u + 0x7FFFu + ((u >> 16) & 1u)) >> 16;   // RNE
    return (ushort)u;
}

// unpack-accumulate 8 bf16 (one uint4) into a[8]
#define ADD8(a, u)                                                  \
    {                                                               \
        a[0] += __uint_as_float((u).x << 16);                       \
        a[1] += __uint_as_float((u).x & 0xFFFF0000u);               \
        a[2] += __uint_as_float((u).y << 16);                       \
        a[3] += __uint_as_float((u).y & 0xFFFF0000u);               \
        a[4] += __uint_as_float((u).z << 16);                       \
        a[5] += __uint_as_float((u).z & 0xFFFF0000u);               \
        a[6] += __uint_as_float((u).w << 16);                       \
        a[7] += __uint_as_float((u).w & 0xFFFF0000u);               \
    }

// ---- fp32 -> bf16 mirror (8 elems/thread) ----
__global__ void k_cvt(const float* __restrict__ x, ushort* __restrict__ xb, int n8) {
    int t = blockIdx.x * blockDim.x + threadIdx.x;
    if (t >= n8) return;
    const float4* p = reinterpret_cast<const float4*>(x) + (size_t)t * 2;
    const float4 v0 = p[0], v1 = p[1];
    uint4 u;
    u.x = (uint)f2bf(v0.x) | ((uint)f2bf(v0.y) << 16);
    u.y = (uint)f2bf(v0.z) | ((uint)f2bf(v0.w) << 16);
    u.z = (uint)f2bf(v1.x) | ((uint)f2bf(v1.y) << 16);
    u.w = (uint)f2bf(v1.z) | ((uint)f2bf(v1.w) << 16);
    reinterpret_cast<uint4*>(xb)[t] = u;
}

// ---- in-degree histogram ----
__global__ void k_hist(const int* __restrict__ dst, int* __restrict__ hist, int E) {
    int e = blockIdx.x * blockDim.x + threadIdx.x;
    if (e < E) atomicAdd(&hist[dst[e]], 1);
}

// ---- scan phase A: per-block (512 elems) partial sums ----
__global__ __launch_bounds__(256) void k_bsum(const int* __restrict__ hist,
                                              int* __restrict__ bsum, int n) {
    const int t = threadIdx.x;
    const int i0 = blockIdx.x * 512 + t * 2;
    int s = 0;
    if (i0 < n) s += hist[i0];
    if (i0 + 1 < n) s += hist[i0 + 1];
    #pragma unroll
    for (int o = 1; o < 64; o <<= 1) s += __shfl_xor(s, o);
    __shared__ int wsum[4];
    if ((t & 63) == 0) wsum[t >> 6] = s;
    __syncthreads();
    if (t == 0) bsum[blockIdx.x] = wsum[0] + wsum[1] + wsum[2] + wsum[3];
}

// ---- scan phase B ----
__global__ __launch_bounds__(128) void k_bscan(int* __restrict__ bsum, int nb) {
    const int t = threadIdx.x;
    const int lane = t & 63, w = t >> 6;
    int v = (t < nb) ? bsum[t] : 0;
    int inc = v;
    #pragma unroll
    for (int o = 1; o < 64; o <<= 1) { int u = __shfl_up(inc, o); if (lane >= o) inc += u; }
    __shared__ int wsum[2];
    if (lane == 63) wsum[w] = inc;
    __syncthreads();
    int off = (w == 1) ? wsum[0] : 0;
    if (t < nb) bsum[t] = off + inc - v;   // exclusive
}

// ---- scan phase C ----
__global__ __launch_bounds__(256) void k_apply(const int* __restrict__ hist,
        const int* __restrict__ bsum, int* __restrict__ row_off,
        int* __restrict__ cursor, int n, int E) {
    const int t = threadIdx.x;
    const int i0 = blockIdx.x * 512 + t * 2;
    const int v0 = (i0 < n) ? hist[i0] : 0;
    const int v1 = (i0 + 1 < n) ? hist[i0 + 1] : 0;
    const int s = v0 + v1;
    const int lane = t & 63, w = t >> 6;
    int inc = s;
    #pragma unroll
    for (int o = 1; o < 64; o <<= 1) { int u = __shfl_up(inc, o); if (lane >= o) inc += u; }
    __shared__ int wsum[4], woff[4];
    if (lane == 63) wsum[w] = inc;
    __syncthreads();
    if (t == 0) { int r = 0; for (int k = 0; k < 4; ++k) { woff[k] = r; r += wsum[k]; } }
    __syncthreads();
    const int ex = bsum[blockIdx.x] + woff[w] + (inc - s);
    if (i0 < n)     { row_off[i0] = ex;          cursor[i0] = ex; }
    if (i0 + 1 < n) { row_off[i0 + 1] = ex + v0; cursor[i0 + 1] = ex + v0; }
    if (blockIdx.x == 0 && t == 0) row_off[n] = E;
}

// ---- CSR fill ----
__global__ void k_fill(const int* __restrict__ src, const int* __restrict__ dst,
                       int* __restrict__ cursor, int* __restrict__ csr, int E) {
    int e = blockIdx.x * blockDim.x + threadIdx.x;
    if (e < E) {
        int p = atomicAdd(&cursor[dst[e]], 1);
        csr[p] = src[e];
    }
}

// ---- fused SAGE layer ----
// Pull: each 16-lane quarter processes its TWO rows interleaved (8 gathers in
// flight) with csr-index prefetch (clamped loads, branch-free).
// GEMM: fp32 from LDS, weights prefetched one k4 ahead.
template<bool NORM, bool BF16SELF>
__global__ __launch_bounds__(256) void k_sage(
    const float* __restrict__ hself, const ushort* __restrict__ hb,
    const int* __restrict__ csr, const int* __restrict__ row_off,
    const float* __restrict__ Wself, const float* __restrict__ Wneigh,
    const float* __restrict__ bias, ushort* __restrict__ outb,
    float* __restrict__ out, int n, int E)
{
    __shared__ float hs[BM][D];
    __shared__ float hn[BM][D];
    const int row0 = blockIdx.x * BM;
    const int tid = threadIdx.x;
    const int lane = tid & 63;
    const int w = tid >> 6;

    // ---- stage self tile ----
    if (!BF16SELF) {
        #pragma unroll
        for (int i = 0; i < 4; ++i) {
            int f = tid + i * 256;
            int r = f >> 5, c4 = f & 31;
            int g = row0 + r;
            float4 v = make_float4(0.f, 0.f, 0.f, 0.f);
            if (g < n) v = *reinterpret_cast<const float4*>(hself + (size_t)g * D + c4 * 4);
            *reinterpret_cast<float4*>(&hs[r][c4 * 4]) = v;
        }
    } else {
        // bank-conflict-free: 4-float chunks at stride 32
        const int r = tid >> 3;
        const int c0 = (tid & 7) * 4;
        const int g = row0 + r;
        #pragma unroll
        for (int j = 0; j < 4; ++j) {
            const int c = c0 + 32 * j;
            float4 v = make_float4(0.f, 0.f, 0.f, 0.f);
            if (g < n) {
                const uint2 u = *reinterpret_cast<const uint2*>(hb + (size_t)g * D + c);
                v.x = __uint_as_float(u.x << 16);
                v.y = __uint_as_float(u.x & 0xFFFF0000u);
                v.z = __uint_as_float(u.y << 16);
                v.w = __uint_as_float(u.y & 0xFFFF0000u);
            }
            *reinterpret_cast<float4*>(&hs[r][c]) = v;
        }
    }

    // ---- pull neighbor means: quarter q owns rows rA = w*8+q and rB = rA+4 ----
    {
        const int q  = lane >> 4;
        const int ql = lane & 15;
        const int Em1 = E - 1;
        const int rA = w * 8 + q;
        const int rB = rA + 4;
        const int gA = row0 + rA, gB = row0 + rB;
        int iA = 0, eA = 0, iB = 0, eB = 0;
        if (gA < n) { iA = row_off[gA]; eA = row_off[gA + 1]; }
        if (gB < n) { iB = row_off[gB]; eB = row_off[gB + 1]; }
        const float dA = (eA > iA) ? 1.0f / (float)(eA - iA) : 0.0f;
        const float dB = (eB > iB) ? 1.0f / (float)(eB - iB) : 0.0f;
        float aA[8], aB[8];
        #pragma unroll
        for (int j = 0; j < 8; ++j) { aA[j] = 0.f; aB[j] = 0.f; }

        const size_t off = (size_t)(ql * 8);
        // prefetched indices at current positions (clamped -> branch-free)
        int sA0 = csr[min(iA + 0, Em1)], sA1 = csr[min(iA + 1, Em1)];
        int sA2 = csr[min(iA + 2, Em1)], sA3 = csr[min(iA + 3, Em1)];
        int sB0 = csr[min(iB + 0, Em1)], sB1 = csr[min(iB + 1, Em1)];
        int sB2 = csr[min(iB + 2, Em1)], sB3 = csr[min(iB + 3, Em1)];

        while (iA + 3 < eA && iB + 3 < eB) {
            const uint4 uA0 = *reinterpret_cast<const uint4*>(hb + (size_t)sA0 * D + off);
            const uint4 uA1 = *reinterpret_cast<const uint4*>(hb + (size_t)sA1 * D + off);
            const uint4 uA2 = *reinterpret_cast<const uint4*>(hb + (size_t)sA2 * D + off);
            const uint4 uA3 = *reinterpret_cast<const uint4*>(hb + (size_t)sA3 * D + off);
            const uint4 uB0 = *reinterpret_cast<const uint4*>(hb + (size_t)sB0 * D + off);
            const uint4 uB1 = *reinterpret_cast<const uint4*>(hb + (size_t)sB1 * D + off);
            const uint4 uB2 = *reinterpret_cast<const uint4*>(hb + (size_t)sB2 * D + off);
            const uint4 uB3 = *reinterpret_cast<const uint4*>(hb + (size_t)sB3 * D + off);
            iA += 4; iB += 4;
            sA0 = csr[min(iA + 0, Em1)]; sA1 = csr[min(iA + 1, Em1)];
            sA2 = csr[min(iA + 2, Em1)]; sA3 = csr[min(iA + 3, Em1)];
            sB0 = csr[min(iB + 0, Em1)]; sB1 = csr[min(iB + 1, Em1)];
            sB2 = csr[min(iB + 2, Em1)]; sB3 = csr[min(iB + 3, Em1)];
            ADD8(aA, uA0); ADD8(aA, uA1); ADD8(aA, uA2); ADD8(aA, uA3);
            ADD8(aB, uB0); ADD8(aB, uB1); ADD8(aB, uB2); ADD8(aB, uB3);
        }
        while (iA + 3 < eA) {
            const uint4 u0 = *reinterpret_cast<const uint4*>(hb + (size_t)sA0 * D + off);
            const uint4 u1 = *reinterpret_cast<const uint4*>(hb + (size_t)sA1 * D + off);
            const uint4 u2 = *reinterpret_cast<const uint4*>(hb + (size_t)sA2 * D + off);
            const uint4 u3 = *reinterpret_cast<const uint4*>(hb + (size_t)sA3 * D + off);
            iA += 4;
            sA0 = csr[min(iA + 0, Em1)]; sA1 = csr[min(iA + 1, Em1)];
            sA2 = csr[min(iA + 2, Em1)]; sA3 = csr[min(iA + 3, Em1)];
            ADD8(aA, u0); ADD8(aA, u1); ADD8(aA, u2); ADD8(aA, u3);
        }
        while (iB + 3 < eB) {
            const uint4 u0 = *reinterpret_cast<const uint4*>(hb + (size_t)sB0 * D + off);
            const uint4 u1 = *reinterpret_cast<const uint4*>(hb + (size_t)sB1 * D + off);
            const uint4 u2 = *reinterpret_cast<const uint4*>(hb + (size_t)sB2 * D + off);
            const uint4 u3 = *reinterpret_cast<const uint4*>(hb + (size_t)sB3 * D + off);
            iB += 4;
            sB0 = csr[min(iB + 0, Em1)]; sB1 = csr[min(iB + 1, Em1)];
            sB2 = csr[min(iB + 2, Em1)]; sB3 = csr[min(iB + 3, Em1)];
            ADD8(aB, u0); ADD8(aB, u1); ADD8(aB, u2); ADD8(aB, u3);
        }
        for (; iA < eA; ++iA) {
            const int s = csr[iA];
            const uint4 u = *reinterpret_cast<const uint4*>(hb + (size_t)s * D + off);
            ADD8(aA, u);
        }
        for (; iB < eB; ++iB) {
            const int s = csr[iB];
            const uint4 u = *reinterpret_cast<const uint4*>(hb + (size_t)s * D + off);
            ADD8(aB, u);
        }
        #pragma unroll
        for (int j = 0; j < 8; ++j) { aA[j] *= dA; aB[j] *= dB; }
        *reinterpret_cast<float4*>(&hn[rA][ql * 8])     = *reinterpret_cast<float4*>(&aA[0]);
        *reinterpret_cast<float4*>(&hn[rA][ql * 8 + 4]) = *reinterpret_cast<float4*>(&aA[4]);
        *reinterpret_cast<float4*>(&hn[rB][ql * 8])     = *reinterpret_cast<float4*>(&aB[0]);
        *reinterpret_cast<float4*>(&hn[rB][ql * 8 + 4]) = *reinterpret_cast<float4*>(&aB[4]);
    }
    __syncthreads();

    // ---- dual GEMM (weights prefetched one k4 ahead) ----
    const int col = tid & 127;
    const int rh = tid >> 7;
    float acc[16];
    #pragma unroll
    for (int r = 0; r < 16; ++r) acc[r] = 0.f;

    float ws[4], wn[4];
    #pragma unroll
    for (int j = 0; j < 4; ++j) {
        ws[j] = Wself[j * D + col];
        wn[j] = Wneigh[j * D + col];
    }
    #pragma unroll 1
    for (int k4 = 0; k4 < 32; ++k4) {
        const int k = k4 * 4;
        const int kn = (k4 < 31) ? k + 4 : k;
        float ws2[4], wn2[4];
        #pragma unroll
        for (int j = 0; j < 4; ++j) {
            ws2[j] = Wself[(kn + j) * D + col];
            wn2[j] = Wneigh[(kn + j) * D + col];
        }
        #pragma unroll
        for (int r = 0; r < 16; ++r) {
            const float4 hv = *reinterpret_cast<const float4*>(&hs[rh * 16 + r][k]);
            const float4 nv = *reinterpret_cast<const float4*>(&hn[rh * 16 + r][k]);
            float t0 = fmaf(hv.x, ws[0], acc[r]);
            t0 = fmaf(hv.y, ws[1], t0);
            t0 = fmaf(hv.z, ws[2], t0);
            t0 = fmaf(hv.w, ws[3], t0);
            t0 = fmaf(nv.x, wn[0], t0);
            t0 = fmaf(nv.y, wn[1], t0);
            t0 = fmaf(nv.z, wn[2], t0);
            t0 = fmaf(nv.w, wn[3], t0);
            acc[r] = t0;
        }
        #pragma unroll
        for (int j = 0; j < 4; ++j) { ws[j] = ws2[j]; wn[j] = wn2[j]; }
    }

    const float bj = bias[col];
    if (!NORM) {
        #pragma unroll
        for (int r = 0; r < 16; ++r) {
            const int g = row0 + rh * 16 + r;
            if (g < n) outb[(size_t)g * D + col] = f2bf(fmaxf(acc[r] + bj, 0.f));
        }
    } else {
        // all threads must finish reading hs/hn as GEMM inputs before reuse
        __syncthreads();
        #pragma unroll
        for (int r = 0; r < 16; ++r) hs[rh * 16 + r][col] = fmaxf(acc[r] + bj, 0.f);
        __syncthreads();
        // bank-conflict-free: 4-float chunks at stride 32
        const int row = tid >> 3;
        const int cb = (tid & 7) * 4;
        float4 vv[4];
        float ssq = 0.f;
        #pragma unroll
        for (int j = 0; j < 4; ++j) {
            vv[j] = *reinterpret_cast<float4*>(&hs[row][cb + 32 * j]);
            ssq += vv[j].x * vv[j].x + vv[j].y * vv[j].y + vv[j].z * vv[j].z + vv[j].w * vv[j].w;
        }
        #pragma unroll
        for (int o = 1; o < 8; o <<= 1) ssq += __shfl_xor(ssq, o);
        const float scale = 1.0f / fmaxf(sqrtf(ssq), 1e-12f);
        const int g = row0 + row;
        if (g < n) {
            #pragma unroll
            for (int j = 0; j < 4; ++j) {
                float4 v = vv[j];
                v.x *= scale; v.y *= scale; v.z *= scale; v.w *= scale;
                *reinterpret_cast<float4*>(out + (size_t)g * D + cb + 32 * j) = v;
            }
        }
    }
}

extern "C" void kernel_launch(void* const* d_in, const int* in_sizes, int n_in,
                              void* d_out, int out_size, void* d_ws, size_t ws_size,
                              hipStream_t stream) {
    const float* x   = (const float*)d_in[0];
    const int*   src = (const int*)d_in[1];
    const int*   dst = (const int*)d_in[2];
    const float* Ws0 = (const float*)d_in[3];
    const float* Wn0 = (const float*)d_in[4];
    const float* b0  = (const float*)d_in[5];
    const float* Ws1 = (const float*)d_in[6];
    const float* Wn1 = (const float*)d_in[7];
    const float* b1  = (const float*)d_in[8];
    float* out = (float*)d_out;
    const int E = in_sizes[1];

    // workspace layout (~29.4 MB)
    ushort* xb     = (ushort*)d_ws;                      // NN*D bf16 = 12.8 MB
    ushort* h1b    = xb + (size_t)NN * D;                // NN*D bf16 = 12.8 MB
    int*    hist   = (int*)(h1b + (size_t)NN * D);       // NN
    int*    bsum   = hist + NN;                          // 128
    int*    row_off= bsum + 128;                         // NN+1
    int*    cursor = row_off + NN + 1;                   // NN
    int*    csr    = cursor + NN;                        // E

    const int nb = (NN + 511) / 512;

    // ---- bf16 mirror of x ----
    k_cvt<<<(NN * D / 8 + 255) / 256, 256, 0, stream>>>(x, xb, NN * D / 8);

    // ---- build CSR ----
    hipMemsetAsync(hist, 0, (size_t)NN * sizeof(int), stream);
    k_hist<<<(E + 255) / 256, 256, 0, stream>>>(dst, hist, E);
    k_bsum<<<nb, 256, 0, stream>>>(hist, bsum, NN);
    k_bscan<<<1, 128, 0, stream>>>(bsum, nb);
    k_apply<<<nb, 256, 0, stream>>>(hist, bsum, row_off, cursor, NN, E);
    k_fill<<<(E + 255) / 256, 256, 0, stream>>>(src, dst, cursor, csr, E);

    // ---- layer 1: self from fp32 x, gather from xb -> h1b (bf16) ----
    k_sage<false, false><<<(NN + BM - 1) / BM, 256, 0, stream>>>(
        x, xb, csr, row_off, Ws0, Wn0, b0, h1b, nullptr, NN, E);

    // ---- layer 2 + normalize: self+gather from h1b -> out (fp32) ----
    k_sage<true, true><<<(NN + BM - 1) / BM, 256, 0, stream>>>(
        nullptr, h1b, csr, row_off, Ws1, Wn1, b1, nullptr, out, NN, E);
}

// Round 8
// 193.675 us; speedup vs baseline: 1.6182x; 1.6182x over previous
//
#include <hip/hip_runtime.h>

#define NN 50000
#define D 128
#define BM 32

typedef unsigned int uint;
typedef unsigned short ushort;
typedef __attribute__((ext_vector_type(8))) short bf16x8;
typedef __attribute__((ext_vector_type(4))) float f32x4;

static __device__ __forceinline__ ushort f2bf(float f) {
    uint u = __float_as_uint(f);
    u = (u + 0x7FFFu + ((u >> 16) & 1u)) >> 16;   // RNE
    return (ushort)u;
}

// unpack-accumulate 8 bf16 (one uint4) into a[8]
#define ADD8(a, u)                                                  \
    {                                                               \
        a[0] += __uint_as_float((u).x << 16);                       \
        a[1] += __uint_as_float((u).x & 0xFFFF0000u);               \
        a[2] += __uint_as_float((u).y << 16);                       \
        a[3] += __uint_as_float((u).y & 0xFFFF0000u);               \
        a[4] += __uint_as_float((u).z << 16);                       \
        a[5] += __uint_as_float((u).z & 0xFFFF0000u);               \
        a[6] += __uint_as_float((u).w << 16);                       \
        a[7] += __uint_as_float((u).w & 0xFFFF0000u);               \
    }

// swizzled LDS address (ushort units) of 16B-chunk ch of row r  (T2/G4 fix:
// without swizzle all 16 lanes of an A-frag ds_read_b128 hit one 4-bank cluster)
static __device__ __forceinline__ int ladr(int r, int ch) {
    return r * D + (((ch) ^ (r & 7)) << 3);
}

// ---- fp32 -> bf16 mirror (8 elems/thread) ----
__global__ void k_cvt(const float* __restrict__ x, ushort* __restrict__ xb, int n8) {
    int t = blockIdx.x * blockDim.x + threadIdx.x;
    if (t >= n8) return;
    const float4* p = reinterpret_cast<const float4*>(x) + (size_t)t * 2;
    const float4 v0 = p[0], v1 = p[1];
    uint4 u;
    u.x = (uint)f2bf(v0.x) | ((uint)f2bf(v0.y) << 16);
    u.y = (uint)f2bf(v0.z) | ((uint)f2bf(v0.w) << 16);
    u.z = (uint)f2bf(v1.x) | ((uint)f2bf(v1.y) << 16);
    u.w = (uint)f2bf(v1.z) | ((uint)f2bf(v1.w) << 16);
    reinterpret_cast<uint4*>(xb)[t] = u;
}

// ---- pack W (fp32 [k][n]) into fragment-major bf16 P[(kt*128+n)*32 + ks] ----
__global__ void k_wpack(const float* __restrict__ W0, const float* __restrict__ W1,
                        const float* __restrict__ W2, const float* __restrict__ W3,
                        ushort* __restrict__ P) {
    int o = blockIdx.x * 256 + threadIdx.x;          // 4 * 16384
    if (o >= 65536) return;
    const int mat = o >> 14;
    const int idx = o & 16383;
    const int kt = idx >> 12;
    const int n  = (idx >> 5) & 127;
    const int ks = idx & 31;
    const float* W = (mat == 0) ? W0 : (mat == 1) ? W1 : (mat == 2) ? W2 : W3;
    P[o] = f2bf(W[(kt * 32 + ks) * D + n]);
}

// ---- in-degree histogram ----
__global__ void k_hist(const int* __restrict__ dst, int* __restrict__ hist, int E) {
    int e = blockIdx.x * blockDim.x + threadIdx.x;
    if (e < E) atomicAdd(&hist[dst[e]], 1);
}

// ---- scan phase A ----
__global__ __launch_bounds__(256) void k_bsum(const int* __restrict__ hist,
                                              int* __restrict__ bsum, int n) {
    const int t = threadIdx.x;
    const int i0 = blockIdx.x * 512 + t * 2;
    int s = 0;
    if (i0 < n) s += hist[i0];
    if (i0 + 1 < n) s += hist[i0 + 1];
    #pragma unroll
    for (int o = 1; o < 64; o <<= 1) s += __shfl_xor(s, o);
    __shared__ int wsum[4];
    if ((t & 63) == 0) wsum[t >> 6] = s;
    __syncthreads();
    if (t == 0) bsum[blockIdx.x] = wsum[0] + wsum[1] + wsum[2] + wsum[3];
}

// ---- scan phase B ----
__global__ __launch_bounds__(128) void k_bscan(int* __restrict__ bsum, int nb) {
    const int t = threadIdx.x;
    const int lane = t & 63, w = t >> 6;
    int v = (t < nb) ? bsum[t] : 0;
    int inc = v;
    #pragma unroll
    for (int o = 1; o < 64; o <<= 1) { int u = __shfl_up(inc, o); if (lane >= o) inc += u; }
    __shared__ int wsum[2];
    if (lane == 63) wsum[w] = inc;
    __syncthreads();
    int off = (w == 1) ? wsum[0] : 0;
    if (t < nb) bsum[t] = off + inc - v;   // exclusive
}

// ---- scan phase C ----
__global__ __launch_bounds__(256) void k_apply(const int* __restrict__ hist,
        const int* __restrict__ bsum, int* __restrict__ row_off,
        int* __restrict__ cursor, int n, int E) {
    const int t = threadIdx.x;
    const int i0 = blockIdx.x * 512 + t * 2;
    const int v0 = (i0 < n) ? hist[i0] : 0;
    const int v1 = (i0 + 1 < n) ? hist[i0 + 1] : 0;
    const int s = v0 + v1;
    const int lane = t & 63, w = t >> 6;
    int inc = s;
    #pragma unroll
    for (int o = 1; o < 64; o <<= 1) { int u = __shfl_up(inc, o); if (lane >= o) inc += u; }
    __shared__ int wsum[4], woff[4];
    if (lane == 63) wsum[w] = inc;
    __syncthreads();
    if (t == 0) { int r = 0; for (int k = 0; k < 4; ++k) { woff[k] = r; r += wsum[k]; } }
    __syncthreads();
    const int ex = bsum[blockIdx.x] + woff[w] + (inc - s);
    if (i0 < n)     { row_off[i0] = ex;          cursor[i0] = ex; }
    if (i0 + 1 < n) { row_off[i0 + 1] = ex + v0; cursor[i0 + 1] = ex + v0; }
    if (blockIdx.x == 0 && t == 0) row_off[n] = E;
}

// ---- CSR fill ----
__global__ void k_fill(const int* __restrict__ src, const int* __restrict__ dst,
                       int* __restrict__ cursor, int* __restrict__ csr, int E) {
    int e = blockIdx.x * blockDim.x + threadIdx.x;
    if (e < E) {
        int p = atomicAdd(&cursor[dst[e]], 1);
        csr[p] = src[e];
    }
}

// ---- fused SAGE layer: pull-mean + dual MFMA GEMM + bias + ReLU (+ L2 norm) ----
// 512 threads = 8 waves. Self+gather both from bf16 mirror hb.
// Pull: 16-lane quarter per row (32 quarters = 32 rows), unroll 4.
// GEMM: mfma_f32_16x16x32_bf16; A from swizzled LDS, B from packed global Wp.
template<bool NORM>
__global__ __launch_bounds__(512, 4) void k_sage(
    const ushort* __restrict__ hb,
    const int* __restrict__ csr, const int* __restrict__ row_off,
    const ushort* __restrict__ Wps, const ushort* __restrict__ Wpn,
    const float* __restrict__ bias, ushort* __restrict__ outb,
    float* __restrict__ out, int n, int E)
{
    __shared__ __align__(16) ushort hsb[BM * D];
    __shared__ __align__(16) ushort hnb[BM * D];
    __shared__ float outt[BM * 132];
    const int row0 = blockIdx.x * BM;
    const int tid = threadIdx.x;
    const int l = tid & 63;
    const int w = tid >> 6;

    // ---- stage self tile (bf16 copy, swizzled) ----
    {
        const int r = tid >> 4;
        const int ch = tid & 15;
        const int g = row0 + r;
        uint4 u = make_uint4(0u, 0u, 0u, 0u);
        if (g < n) u = *reinterpret_cast<const uint4*>(hb + (size_t)g * D + ch * 8);
        *reinterpret_cast<uint4*>(&hsb[ladr(r, ch)]) = u;
    }

    // ---- pull neighbor mean for row r = tid>>4, channels (tid&15)*8..+8 ----
    {
        const int r = tid >> 4;
        const int ql = tid & 15;
        const int g = row0 + r;
        int i = 0, e = 0;
        if (g < n) { i = row_off[g]; e = row_off[g + 1]; }
        const float invd = (e > i) ? 1.0f / (float)(e - i) : 0.0f;
        float a[8];
        #pragma unroll
        for (int j = 0; j < 8; ++j) a[j] = 0.f;
        const size_t off = (size_t)(ql * 8);
        for (; i + 3 < e; i += 4) {
            const int s0 = csr[i], s1 = csr[i + 1], s2 = csr[i + 2], s3 = csr[i + 3];
            const uint4 u0 = *reinterpret_cast<const uint4*>(hb + (size_t)s0 * D + off);
            const uint4 u1 = *reinterpret_cast<const uint4*>(hb + (size_t)s1 * D + off);
            const uint4 u2 = *reinterpret_cast<const uint4*>(hb + (size_t)s2 * D + off);
            const uint4 u3 = *reinterpret_cast<const uint4*>(hb + (size_t)s3 * D + off);
            ADD8(a, u0); ADD8(a, u1); ADD8(a, u2); ADD8(a, u3);
        }
        for (; i < e; ++i) {
            const int s0 = csr[i];
            const uint4 u0 = *reinterpret_cast<const uint4*>(hb + (size_t)s0 * D + off);
            ADD8(a, u0);
        }
        uint4 u;
        u.x = (uint)f2bf(a[0] * invd) | ((uint)f2bf(a[1] * invd) << 16);
        u.y = (uint)f2bf(a[2] * invd) | ((uint)f2bf(a[3] * invd) << 16);
        u.z = (uint)f2bf(a[4] * invd) | ((uint)f2bf(a[5] * invd) << 16);
        u.w = (uint)f2bf(a[6] * invd) | ((uint)f2bf(a[7] * invd) << 16);
        *reinterpret_cast<uint4*>(&hnb[ladr(r, ql)]) = u;
    }
    __syncthreads();

    // ---- MFMA: wave w -> m-tile (w>>2), n-tiles (w&3)*2, +1 ----
    {
        const int mt = w >> 2;
        const int ntA = (w & 3) * 2;
        const int rA = mt * 16 + (l & 15);
        const int kg = l >> 4;
        f32x4 acc0 = {0.f, 0.f, 0.f, 0.f};
        f32x4 acc1 = {0.f, 0.f, 0.f, 0.f};
        #pragma unroll
        for (int kt = 0; kt < 4; ++kt) {
            const int kc = kt * 4 + kg;
            const bf16x8 as = *reinterpret_cast<const bf16x8*>(&hsb[ladr(rA, kc)]);
            const bf16x8 an = *reinterpret_cast<const bf16x8*>(&hnb[ladr(rA, kc)]);
            const size_t wo0 = (size_t)(kt * 128 + ntA * 16 + (l & 15)) * 32 + kg * 8;
            const size_t wo1 = wo0 + 16 * 32;
            const bf16x8 bs0 = *reinterpret_cast<const bf16x8*>(Wps + wo0);
            const bf16x8 bn0 = *reinterpret_cast<const bf16x8*>(Wpn + wo0);
            const bf16x8 bs1 = *reinterpret_cast<const bf16x8*>(Wps + wo1);
            const bf16x8 bn1 = *reinterpret_cast<const bf16x8*>(Wpn + wo1);
            acc0 = __builtin_amdgcn_mfma_f32_16x16x32_bf16(as, bs0, acc0, 0, 0, 0);
            acc0 = __builtin_amdgcn_mfma_f32_16x16x32_bf16(an, bn0, acc0, 0, 0, 0);
            acc1 = __builtin_amdgcn_mfma_f32_16x16x32_bf16(as, bs1, acc1, 0, 0, 0);
            acc1 = __builtin_amdgcn_mfma_f32_16x16x32_bf16(an, bn1, acc1, 0, 0, 0);
        }
        // bias + relu into padded fp32 LDS tile (C/D: col=l&15, row=kg*4+i)
        const int c0 = ntA * 16 + (l & 15);
        const float bv0 = bias[c0], bv1 = bias[c0 + 16];
        #pragma unroll
        for (int i2 = 0; i2 < 4; ++i2) {
            const int rr = mt * 16 + kg * 4 + i2;
            outt[rr * 132 + c0]      = fmaxf(acc0[i2] + bv0, 0.f);
            outt[rr * 132 + c0 + 16] = fmaxf(acc1[i2] + bv1, 0.f);
        }
    }
    __syncthreads();

    // ---- epilogue: row r = tid>>4, channels (tid&15)*8..+8 ----
    {
        const int r = tid >> 4;
        const int c = (tid & 15) * 8;
        const int g = row0 + r;
        float4 v0 = *reinterpret_cast<const float4*>(&outt[r * 132 + c]);
        float4 v1 = *reinterpret_cast<const float4*>(&outt[r * 132 + c + 4]);
        if (!NORM) {
            if (g < n) {
                uint4 u;
                u.x = (uint)f2bf(v0.x) | ((uint)f2bf(v0.y) << 16);
                u.y = (uint)f2bf(v0.z) | ((uint)f2bf(v0.w) << 16);
                u.z = (uint)f2bf(v1.x) | ((uint)f2bf(v1.y) << 16);
                u.w = (uint)f2bf(v1.z) | ((uint)f2bf(v1.w) << 16);
                *reinterpret_cast<uint4*>(outb + (size_t)g * D + c) = u;
            }
        } else {
            float ssq = v0.x * v0.x + v0.y * v0.y + v0.z * v0.z + v0.w * v0.w
                      + v1.x * v1.x + v1.y * v1.y + v1.z * v1.z + v1.w * v1.w;
            #pragma unroll
            for (int o = 1; o < 16; o <<= 1) ssq += __shfl_xor(ssq, o);
            const float scale = 1.0f / fmaxf(sqrtf(ssq), 1e-12f);
            if (g < n) {
                v0.x *= scale; v0.y *= scale; v0.z *= scale; v0.w *= scale;
                v1.x *= scale; v1.y *= scale; v1.z *= scale; v1.w *= scale;
                *reinterpret_cast<float4*>(out + (size_t)g * D + c)     = v0;
                *reinterpret_cast<float4*>(out + (size_t)g * D + c + 4) = v1;
            }
        }
    }
}

extern "C" void kernel_launch(void* const* d_in, const int* in_sizes, int n_in,
                              void* d_out, int out_size, void* d_ws, size_t ws_size,
                              hipStream_t stream) {
    const float* x   = (const float*)d_in[0];
    const int*   src = (const int*)d_in[1];
    const int*   dst = (const int*)d_in[2];
    const float* Ws0 = (const float*)d_in[3];
    const float* Wn0 = (const float*)d_in[4];
    const float* b0  = (const float*)d_in[5];
    const float* Ws1 = (const float*)d_in[6];
    const float* Wn1 = (const float*)d_in[7];
    const float* b1  = (const float*)d_in[8];
    float* out = (float*)d_out;
    const int E = in_sizes[1];

    // workspace layout (~25.8 MB + ints)
    ushort* xb     = (ushort*)d_ws;                      // NN*D bf16 = 12.8 MB
    ushort* h1b    = xb + (size_t)NN * D;                // NN*D bf16 = 12.8 MB
    ushort* Wp     = h1b + (size_t)NN * D;               // 4 * 16384 bf16 = 128 KB
    int*    hist   = (int*)(Wp + 65536);                 // NN
    int*    bsum   = hist + NN;                          // 128
    int*    row_off= bsum + 128;                         // NN+1
    int*    cursor = row_off + NN + 1;                   // NN
    int*    csr    = cursor + NN;                        // E

    ushort* Wps0 = Wp;
    ushort* Wpn0 = Wp + 16384;
    ushort* Wps1 = Wp + 32768;
    ushort* Wpn1 = Wp + 49152;

    const int nb = (NN + 511) / 512;

    // ---- bf16 mirror of x + packed bf16 weights ----
    k_cvt<<<(NN * D / 8 + 255) / 256, 256, 0, stream>>>(x, xb, NN * D / 8);
    k_wpack<<<256, 256, 0, stream>>>(Ws0, Wn0, Ws1, Wn1, Wp);

    // ---- build CSR ----
    hipMemsetAsync(hist, 0, (size_t)NN * sizeof(int), stream);
    k_hist<<<(E + 255) / 256, 256, 0, stream>>>(dst, hist, E);
    k_bsum<<<nb, 256, 0, stream>>>(hist, bsum, NN);
    k_bscan<<<1, 128, 0, stream>>>(bsum, nb);
    k_apply<<<nb, 256, 0, stream>>>(hist, bsum, row_off, cursor, NN, E);
    k_fill<<<(E + 255) / 256, 256, 0, stream>>>(src, dst, cursor, csr, E);

    // ---- layer 1: xb -> h1b (bf16) ----
    k_sage<false><<<(NN + BM - 1) / BM, 512, 0, stream>>>(
        xb, csr, row_off, Wps0, Wpn0, b0, h1b, nullptr, NN, E);

    // ---- layer 2 + normalize: h1b -> out (fp32) ----
    k_sage<true><<<(NN + BM - 1) / BM, 512, 0, stream>>>(
        h1b, csr, row_off, Wps1, Wpn1, b1, nullptr, out, NN, E);
}

// Round 9
// 178.087 us; speedup vs baseline: 1.7598x; 1.0875x over previous
//
#include <hip/hip_runtime.h>

#define NN 50000
#define D 128
#define BM 32
#define SL 6250              // NN/8, dst-slice width

typedef unsigned int uint;
typedef unsigned short ushort;
typedef __attribute__((ext_vector_type(8))) short bf16x8;
typedef __attribute__((ext_vector_type(4))) float f32x4;

static __device__ __forceinline__ ushort f2bf(float f) {
    uint u = __float_as_uint(f);
    u = (u + 0x7FFFu + ((u >> 16) & 1u)) >> 16;   // RNE
    return (ushort)u;
}

// unpack-accumulate 8 bf16 (one uint4) into a[8]
#define ADD8(a, u)                                                  \
    {                                                               \
        a[0] += __uint_as_float((u).x << 16);                       \
        a[1] += __uint_as_float((u).x & 0xFFFF0000u);               \
        a[2] += __uint_as_float((u).y << 16);                       \
        a[3] += __uint_as_float((u).y & 0xFFFF0000u);               \
        a[4] += __uint_as_float((u).z << 16);                       \
        a[5] += __uint_as_float((u).z & 0xFFFF0000u);               \
        a[6] += __uint_as_float((u).w << 16);                       \
        a[7] += __uint_as_float((u).w & 0xFFFF0000u);               \
    }

// swizzled LDS address (ushort units) of 16B-chunk ch of row r
static __device__ __forceinline__ int ladr(int r, int ch) {
    return r * D + (((ch) ^ (r & 7)) << 3);
}

// ---- fused prep: [cvt 3125 blocks | wpack 256 blocks | sliced hist 1024 blocks] ----
__global__ __launch_bounds__(256) void k_prep(
    const float* __restrict__ x, ushort* __restrict__ xb,
    const float* __restrict__ W0, const float* __restrict__ W1,
    const float* __restrict__ W2, const float* __restrict__ W3,
    ushort* __restrict__ P,
    const int* __restrict__ dst, int* __restrict__ hist, int E)
{
    const int bid = blockIdx.x;
    if (bid < 3125) {
        // fp32 -> bf16 mirror, 8 elems/thread (3125*256 = 800000 = NN*D/8 exactly)
        const int t = bid * 256 + threadIdx.x;
        const float4* p = reinterpret_cast<const float4*>(x) + (size_t)t * 2;
        const float4 v0 = p[0], v1 = p[1];
        uint4 u;
        u.x = (uint)f2bf(v0.x) | ((uint)f2bf(v0.y) << 16);
        u.y = (uint)f2bf(v0.z) | ((uint)f2bf(v0.w) << 16);
        u.z = (uint)f2bf(v1.x) | ((uint)f2bf(v1.y) << 16);
        u.w = (uint)f2bf(v1.z) | ((uint)f2bf(v1.w) << 16);
        reinterpret_cast<uint4*>(xb)[t] = u;
    } else if (bid < 3125 + 256) {
        // pack W (fp32 [k][n]) into fragment-major bf16 P[(kt*128+n)*32+ks]
        const int o = (bid - 3125) * 256 + threadIdx.x;      // < 65536
        const int mat = o >> 14;
        const int idx = o & 16383;
        const int kt = idx >> 12;
        const int n  = (idx >> 5) & 127;
        const int ks = idx & 31;
        const float* W = (mat == 0) ? W0 : (mat == 1) ? W1 : (mat == 2) ? W2 : W3;
        P[o] = f2bf(W[(kt * 32 + ks) * D + n]);
    } else {
        // sliced in-degree histogram: slice = hb&7 (consistent block->XCD affinity)
        const int hb = bid - (3125 + 256);
        const int s = hb & 7;
        const int lo = s * SL, hi = lo + SL;
        const int bs = hb >> 3;                               // 0..127
        for (int e = bs * 256 + (int)threadIdx.x; e < E; e += 128 * 256) {
            const int d = dst[e];
            if (d >= lo && d < hi) atomicAdd(&hist[d], 1);
        }
    }
}

// ---- scan phase A ----
__global__ __launch_bounds__(256) void k_bsum(const int* __restrict__ hist,
                                              int* __restrict__ bsum, int n) {
    const int t = threadIdx.x;
    const int i0 = blockIdx.x * 512 + t * 2;
    int s = 0;
    if (i0 < n) s += hist[i0];
    if (i0 + 1 < n) s += hist[i0 + 1];
    #pragma unroll
    for (int o = 1; o < 64; o <<= 1) s += __shfl_xor(s, o);
    __shared__ int wsum[4];
    if ((t & 63) == 0) wsum[t >> 6] = s;
    __syncthreads();
    if (t == 0) bsum[blockIdx.x] = wsum[0] + wsum[1] + wsum[2] + wsum[3];
}

// ---- scan phase B ----
__global__ __launch_bounds__(128) void k_bscan(int* __restrict__ bsum, int nb) {
    const int t = threadIdx.x;
    const int lane = t & 63, w = t >> 6;
    int v = (t < nb) ? bsum[t] : 0;
    int inc = v;
    #pragma unroll
    for (int o = 1; o < 64; o <<= 1) { int u = __shfl_up(inc, o); if (lane >= o) inc += u; }
    __shared__ int wsum[2];
    if (lane == 63) wsum[w] = inc;
    __syncthreads();
    int off = (w == 1) ? wsum[0] : 0;
    if (t < nb) bsum[t] = off + inc - v;   // exclusive
}

// ---- scan phase C ----
__global__ __launch_bounds__(256) void k_apply(const int* __restrict__ hist,
        const int* __restrict__ bsum, int* __restrict__ row_off,
        int* __restrict__ cursor, int n, int E) {
    const int t = threadIdx.x;
    const int i0 = blockIdx.x * 512 + t * 2;
    const int v0 = (i0 < n) ? hist[i0] : 0;
    const int v1 = (i0 + 1 < n) ? hist[i0 + 1] : 0;
    const int s = v0 + v1;
    const int lane = t & 63, w = t >> 6;
    int inc = s;
    #pragma unroll
    for (int o = 1; o < 64; o <<= 1) { int u = __shfl_up(inc, o); if (lane >= o) inc += u; }
    __shared__ int wsum[4], woff[4];
    if (lane == 63) wsum[w] = inc;
    __syncthreads();
    if (t == 0) { int r = 0; for (int k = 0; k < 4; ++k) { woff[k] = r; r += wsum[k]; } }
    __syncthreads();
    const int ex = bsum[blockIdx.x] + woff[w] + (inc - s);
    if (i0 < n)     { row_off[i0] = ex;          cursor[i0] = ex; }
    if (i0 + 1 < n) { row_off[i0 + 1] = ex + v0; cursor[i0 + 1] = ex + v0; }
    if (blockIdx.x == 0 && t == 0) row_off[n] = E;
}

// ---- sliced CSR fill: slice = bid&7 -> XCD-local csr region, L2-coalesced writes ----
__global__ __launch_bounds__(256) void k_fill_s(const int* __restrict__ src,
        const int* __restrict__ dst, int* __restrict__ cursor,
        int* __restrict__ csr, int E) {
    const int s = blockIdx.x & 7;
    const int lo = s * SL, hi = lo + SL;
    const int bs = blockIdx.x >> 3;
    const int stride = (gridDim.x >> 3) * 256;
    for (int e = bs * 256 + (int)threadIdx.x; e < E; e += stride) {
        const int d = dst[e];
        const int sv = src[e];
        if (d >= lo && d < hi) {
            const int p = atomicAdd(&cursor[d], 1);
            csr[p] = sv;
        }
    }
}

// ---- fused SAGE layer: pull-mean + dual MFMA GEMM + bias + ReLU (+ L2 norm) ----
template<bool NORM>
__global__ __launch_bounds__(512, 4) void k_sage(
    const ushort* __restrict__ hb,
    const int* __restrict__ csr, const int* __restrict__ row_off,
    const ushort* __restrict__ Wps, const ushort* __restrict__ Wpn,
    const float* __restrict__ bias, ushort* __restrict__ outb,
    float* __restrict__ out, int n, int E)
{
    __shared__ __align__(16) ushort hsb[BM * D];
    __shared__ __align__(16) ushort hnb[BM * D];
    __shared__ float outt[BM * 132];
    const int row0 = blockIdx.x * BM;
    const int tid = threadIdx.x;
    const int l = tid & 63;
    const int w = tid >> 6;

    // ---- stage self tile (bf16 copy, swizzled) ----
    {
        const int r = tid >> 4;
        const int ch = tid & 15;
        const int g = row0 + r;
        uint4 u = make_uint4(0u, 0u, 0u, 0u);
        if (g < n) u = *reinterpret_cast<const uint4*>(hb + (size_t)g * D + ch * 8);
        *reinterpret_cast<uint4*>(&hsb[ladr(r, ch)]) = u;
    }

    // ---- pull neighbor mean for row r = tid>>4, channels (tid&15)*8..+8 ----
    {
        const int r = tid >> 4;
        const int ql = tid & 15;
        const int g = row0 + r;
        int i = 0, e = 0;
        if (g < n) { i = row_off[g]; e = row_off[g + 1]; }
        const float invd = (e > i) ? 1.0f / (float)(e - i) : 0.0f;
        float a[8];
        #pragma unroll
        for (int j = 0; j < 8; ++j) a[j] = 0.f;
        const size_t off = (size_t)(ql * 8);
        for (; i + 3 < e; i += 4) {
            const int s0 = csr[i], s1 = csr[i + 1], s2 = csr[i + 2], s3 = csr[i + 3];
            const uint4 u0 = *reinterpret_cast<const uint4*>(hb + (size_t)s0 * D + off);
            const uint4 u1 = *reinterpret_cast<const uint4*>(hb + (size_t)s1 * D + off);
            const uint4 u2 = *reinterpret_cast<const uint4*>(hb + (size_t)s2 * D + off);
            const uint4 u3 = *reinterpret_cast<const uint4*>(hb + (size_t)s3 * D + off);
            ADD8(a, u0); ADD8(a, u1); ADD8(a, u2); ADD8(a, u3);
        }
        for (; i < e; ++i) {
            const int s0 = csr[i];
            const uint4 u0 = *reinterpret_cast<const uint4*>(hb + (size_t)s0 * D + off);
            ADD8(a, u0);
        }
        uint4 u;
        u.x = (uint)f2bf(a[0] * invd) | ((uint)f2bf(a[1] * invd) << 16);
        u.y = (uint)f2bf(a[2] * invd) | ((uint)f2bf(a[3] * invd) << 16);
        u.z = (uint)f2bf(a[4] * invd) | ((uint)f2bf(a[5] * invd) << 16);
        u.w = (uint)f2bf(a[6] * invd) | ((uint)f2bf(a[7] * invd) << 16);
        *reinterpret_cast<uint4*>(&hnb[ladr(r, ql)]) = u;
    }
    __syncthreads();

    // ---- MFMA: wave w -> m-tile (w>>2), n-tiles (w&3)*2, +1 ----
    {
        const int mt = w >> 2;
        const int ntA = (w & 3) * 2;
        const int rA = mt * 16 + (l & 15);
        const int kg = l >> 4;
        f32x4 acc0 = {0.f, 0.f, 0.f, 0.f};
        f32x4 acc1 = {0.f, 0.f, 0.f, 0.f};
        #pragma unroll
        for (int kt = 0; kt < 4; ++kt) {
            const int kc = kt * 4 + kg;
            const bf16x8 as = *reinterpret_cast<const bf16x8*>(&hsb[ladr(rA, kc)]);
            const bf16x8 an = *reinterpret_cast<const bf16x8*>(&hnb[ladr(rA, kc)]);
            const size_t wo0 = (size_t)(kt * 128 + ntA * 16 + (l & 15)) * 32 + kg * 8;
            const size_t wo1 = wo0 + 16 * 32;
            const bf16x8 bs0 = *reinterpret_cast<const bf16x8*>(Wps + wo0);
            const bf16x8 bn0 = *reinterpret_cast<const bf16x8*>(Wpn + wo0);
            const bf16x8 bs1 = *reinterpret_cast<const bf16x8*>(Wps + wo1);
            const bf16x8 bn1 = *reinterpret_cast<const bf16x8*>(Wpn + wo1);
            acc0 = __builtin_amdgcn_mfma_f32_16x16x32_bf16(as, bs0, acc0, 0, 0, 0);
            acc0 = __builtin_amdgcn_mfma_f32_16x16x32_bf16(an, bn0, acc0, 0, 0, 0);
            acc1 = __builtin_amdgcn_mfma_f32_16x16x32_bf16(as, bs1, acc1, 0, 0, 0);
            acc1 = __builtin_amdgcn_mfma_f32_16x16x32_bf16(an, bn1, acc1, 0, 0, 0);
        }
        const int c0 = ntA * 16 + (l & 15);
        const float bv0 = bias[c0], bv1 = bias[c0 + 16];
        #pragma unroll
        for (int i2 = 0; i2 < 4; ++i2) {
            const int rr = mt * 16 + kg * 4 + i2;
            outt[rr * 132 + c0]      = fmaxf(acc0[i2] + bv0, 0.f);
            outt[rr * 132 + c0 + 16] = fmaxf(acc1[i2] + bv1, 0.f);
        }
    }
    __syncthreads();

    // ---- epilogue: row r = tid>>4, channels (tid&15)*8..+8 ----
    {
        const int r = tid >> 4;
        const int c = (tid & 15) * 8;
        const int g = row0 + r;
        float4 v0 = *reinterpret_cast<const float4*>(&outt[r * 132 + c]);
        float4 v1 = *reinterpret_cast<const float4*>(&outt[r * 132 + c + 4]);
        if (!NORM) {
            if (g < n) {
                uint4 u;
                u.x = (uint)f2bf(v0.x) | ((uint)f2bf(v0.y) << 16);
                u.y = (uint)f2bf(v0.z) | ((uint)f2bf(v0.w) << 16);
                u.z = (uint)f2bf(v1.x) | ((uint)f2bf(v1.y) << 16);
                u.w = (uint)f2bf(v1.z) | ((uint)f2bf(v1.w) << 16);
                *reinterpret_cast<uint4*>(outb + (size_t)g * D + c) = u;
            }
        } else {
            float ssq = v0.x * v0.x + v0.y * v0.y + v0.z * v0.z + v0.w * v0.w
                      + v1.x * v1.x + v1.y * v1.y + v1.z * v1.z + v1.w * v1.w;
            #pragma unroll
            for (int o = 1; o < 16; o <<= 1) ssq += __shfl_xor(ssq, o);
            const float scale = 1.0f / fmaxf(sqrtf(ssq), 1e-12f);
            if (g < n) {
                v0.x *= scale; v0.y *= scale; v0.z *= scale; v0.w *= scale;
                v1.x *= scale; v1.y *= scale; v1.z *= scale; v1.w *= scale;
                *reinterpret_cast<float4*>(out + (size_t)g * D + c)     = v0;
                *reinterpret_cast<float4*>(out + (size_t)g * D + c + 4) = v1;
            }
        }
    }
}

extern "C" void kernel_launch(void* const* d_in, const int* in_sizes, int n_in,
                              void* d_out, int out_size, void* d_ws, size_t ws_size,
                              hipStream_t stream) {
    const float* x   = (const float*)d_in[0];
    const int*   src = (const int*)d_in[1];
    const int*   dst = (const int*)d_in[2];
    const float* Ws0 = (const float*)d_in[3];
    const float* Wn0 = (const float*)d_in[4];
    const float* b0  = (const float*)d_in[5];
    const float* Ws1 = (const float*)d_in[6];
    const float* Wn1 = (const float*)d_in[7];
    const float* b1  = (const float*)d_in[8];
    float* out = (float*)d_out;
    const int E = in_sizes[1];

    // workspace layout (~25.8 MB + ints)
    ushort* xb     = (ushort*)d_ws;                      // NN*D bf16 = 12.8 MB
    ushort* h1b    = xb + (size_t)NN * D;                // NN*D bf16 = 12.8 MB
    ushort* Wp     = h1b + (size_t)NN * D;               // 4 * 16384 bf16 = 128 KB
    int*    hist   = (int*)(Wp + 65536);                 // NN
    int*    bsum   = hist + NN;                          // 128
    int*    row_off= bsum + 128;                         // NN+1
    int*    cursor = row_off + NN + 1;                   // NN
    int*    csr    = cursor + NN;                        // E

    ushort* Wps0 = Wp;
    ushort* Wpn0 = Wp + 16384;
    ushort* Wps1 = Wp + 32768;
    ushort* Wpn1 = Wp + 49152;

    const int nb = (NN + 511) / 512;                     // 98 scan blocks

    // ---- prep: hist must start from zero ----
    hipMemsetAsync(hist, 0, (size_t)NN * sizeof(int), stream);
    k_prep<<<3125 + 256 + 1024, 256, 0, stream>>>(x, xb, Ws0, Wn0, Ws1, Wn1, Wp,
                                                  dst, hist, E);
    k_bsum<<<nb, 256, 0, stream>>>(hist, bsum, NN);
    k_bscan<<<1, 128, 0, stream>>>(bsum, nb);
    k_apply<<<nb, 256, 0, stream>>>(hist, bsum, row_off, cursor, NN, E);
    k_fill_s<<<1024, 256, 0, stream>>>(src, dst, cursor, csr, E);

    // ---- layer 1: xb -> h1b (bf16) ----
    k_sage<false><<<(NN + BM - 1) / BM, 512, 0, stream>>>(
        xb, csr, row_off, Wps0, Wpn0, b0, h1b, nullptr, NN, E);

    // ---- layer 2 + normalize: h1b -> out (fp32) ----
    k_sage<true><<<(NN + BM - 1) / BM, 512, 0, stream>>>(
        h1b, csr, row_off, Wps1, Wpn1, b1, nullptr, out, NN, E);
}